// Round 1
// 3413.454 us; speedup vs baseline: 1.1753x; 1.1753x over previous
//
#include <hip/hip_runtime.h>
#include <hip/hip_bf16.h>

typedef unsigned short u16;

#define B_  4
#define S_  4096
#define D_  1024
#define A_  1024
#define FF_ 4096
#define NB  4
#define LN_EPS 1e-6f

typedef __bf16 bf16x8 __attribute__((ext_vector_type(8)));
typedef float  floatx4 __attribute__((ext_vector_type(4)));

__device__ __forceinline__ float gelu_f(float x) {
    // jax.nn.gelu approximate=True: 0.5x(1+tanh(u)) == x * sigmoid(2u)
    float u = 0.7978845608028654f * (x + 0.044715f * x * x * x);
    return x / (1.0f + __expf(-2.0f * u));
}

__device__ __forceinline__ u16 f2bf(float f) {
    __bf16 h = (__bf16)f;   // RNE convert
    return *(u16*)&h;
}

__device__ __forceinline__ float bf2f(u16 u) {
    unsigned int v = ((unsigned int)u) << 16;
    float f;
    __builtin_memcpy(&f, &v, 4);
    return f;
}

// async global->LDS 16B (direct-to-LDS DMA; dest = wave-uniform base + lane*16)
__device__ __forceinline__ void gload_lds16(const u16* g, u16* l) {
    __builtin_amdgcn_global_load_lds(
        (const __attribute__((address_space(1))) void*)g,
        (__attribute__((address_space(3))) void*)l, 16, 0, 0);
}

// ---------------- zero the KV/Ksum accumulators ------------------------------
__global__ __launch_bounds__(256) void zero_kv(float* __restrict__ p) {
    int idx = (blockIdx.x * 256 + threadIdx.x) * 4;   // 8 blocks -> 8192 floats
    *(float4*)(p + idx) = (float4){0.f, 0.f, 0.f, 0.f};
}

// ---------------- weight transpose + downcast: W[K,N] f32 -> Wt[N,K] bf16 ----
__global__ __launch_bounds__(256) void transpose_w(const float* __restrict__ W,
                                                   u16* __restrict__ Wt,
                                                   int K, int N) {
    __shared__ float tile[32][33];
    int tx = threadIdx.x;         // 0..31
    int ty = threadIdx.y;         // 0..7
    int n0 = blockIdx.x * 32;
    int k0 = blockIdx.y * 32;
#pragma unroll
    for (int r = 0; r < 4; r++) {
        int k = k0 + ty + r * 8;
        tile[ty + r * 8][tx] = W[(size_t)k * N + n0 + tx];
    }
    __syncthreads();
#pragma unroll
    for (int r = 0; r < 4; r++) {
        int n = n0 + ty + r * 8;
        Wt[(size_t)n * K + k0 + tx] = f2bf(tile[tx][ty + r * 8]);
    }
}

// =============================================================================
// 256x256 8-phase bf16 MFMA GEMM (m201-style template, plain HIP).
//   C[M,N] = act(A[M,K] @ Bt[N,K]^T + bias)
// 8 waves (2Mx4N), BK=64, 128KB LDS double-buffer, XOR slot-swizzle
// (linear global_load_lds dest + inverse-swizzled global src + swizzled read),
// counted vmcnt(4) at phases 4/8 only, setprio(1) around MFMA clusters,
// bijective XCD swizzle (all grids % 8 == 0).
// MODE: 0=elu+1  1=identity  2=gelu(gelu)  3=gelu
//       4=QKV scatter (seg0/1 -> elu+1 -> out/outK; seg2 -> ident -> outV)
//       5=identity, no bias (bf16 partial store)
//       6=gelu(acc + bias + bf16_read(out))  (split-K finish, read-mod-write)
// =============================================================================
#define BAR  { asm volatile("" ::: "memory"); __builtin_amdgcn_s_barrier(); \
               asm volatile("" ::: "memory"); }
#define VMC4 asm volatile("s_waitcnt vmcnt(4)" ::: "memory")
#define PRIO1 __builtin_amdgcn_s_setprio(1)
#define PRIO0 __builtin_amdgcn_s_setprio(0)

#define STG(ARR, P, LD, BUF, H, KT) {                                          \
    const u16* s_ = (P) + (size_t)((H) * 128) * (LD) + (KT) * 64;              \
    u16* d_ = &ARR[BUF][(H) * 8192 + t * 8];                                   \
    gload_lds16(s_, d_);                                                       \
    gload_lds16(s_ + (size_t)64 * (LD), d_ + 4096); }

#define LDA4(BUF, IH) {                                                        \
    _Pragma("unroll") for (int ii = 0; ii < 4; ii++) {                         \
        const u16* p_ = &As[BUF][aro + ((IH) * 4 + ii) * 1024];                \
        a[ii][0] = *(const bf16x8*)(p_ + sl0);                                 \
        a[ii][1] = *(const bf16x8*)(p_ + sl1); } }

#define LDB2(BUF, JH) {                                                        \
    _Pragma("unroll") for (int jj = 0; jj < 2; jj++) {                         \
        const u16* p_ = &Bs[BUF][bro + ((JH) * 2 + jj) * 1024];                \
        b[(JH) * 2 + jj][0] = *(const bf16x8*)(p_ + sl0);                      \
        b[(JH) * 2 + jj][1] = *(const bf16x8*)(p_ + sl1); } }

#define MM(IH, JH) {                                                           \
    _Pragma("unroll") for (int ii = 0; ii < 4; ii++)                           \
    _Pragma("unroll") for (int jj = 0; jj < 2; jj++)                           \
    _Pragma("unroll") for (int s = 0; s < 2; s++)                              \
        acc[(IH) * 4 + ii][(JH) * 2 + jj] =                                    \
            __builtin_amdgcn_mfma_f32_16x16x32_bf16(                           \
                a[ii][s], b[(JH) * 2 + jj][s],                                 \
                acc[(IH) * 4 + ii][(JH) * 2 + jj], 0, 0, 0); }

template <int MODE>
__global__ __launch_bounds__(512, 2) void gemm256(
    const u16* __restrict__ Amat, const u16* __restrict__ Bt,
    const float* __restrict__ bias, u16* __restrict__ out,
    int M, int N, int K, int gx, int ldb,
    u16* __restrict__ outK, u16* __restrict__ outV,
    const float* __restrict__ biasK, const float* __restrict__ biasV)
{
    __shared__ u16 As[2][16384];   // 64 KB  (two 256x64 bf16 tiles)
    __shared__ u16 Bs[2][16384];   // 64 KB

    // bijective XCD swizzle (grid is a multiple of 8 for all launches)
    const int nwg  = (int)gridDim.x;
    const int cpx  = nwg >> 3;
    const int wgid = ((int)blockIdx.x & 7) * cpx + ((int)blockIdx.x >> 3);
    const int bx = wgid % gx;
    const int by = wgid / gx;
    const int m0 = by * 256, n0 = bx * 256;

    const int t    = threadIdx.x;
    const int wid  = t >> 6, lane = t & 63;
    const int wm   = wid >> 2, wn = wid & 3;   // 2 x 4 waves
    const int lm   = lane & 15, quad = lane >> 4;

    // staging source (per-lane): row trow(+h*128+64u); 16B slot inverse-swizzled
    const int trow  = t >> 3;
    const int tslot = (t & 7) ^ (trow & 7);
    const u16* pa = Amat + (size_t)(m0 + trow) * K   + tslot * 8;
    const u16* pb = Bt   + (size_t)(n0 + trow) * ldb + tslot * 8;

    // LDS fragment-read bases (shorts); slot XOR makes reads bank-uniform
    const int aro = (wm * 128 + lm) * 64;
    const int bro = (wn * 64  + lm) * 64;
    const int sl0 = ((0 * 4 + quad) ^ (lm & 7)) * 8;
    const int sl1 = ((1 * 4 + quad) ^ (lm & 7)) * 8;

    floatx4 acc[8][4];
#pragma unroll
    for (int i = 0; i < 8; i++)
#pragma unroll
        for (int j = 0; j < 4; j++) acc[i][j] = (floatx4){0.f, 0.f, 0.f, 0.f};

    bf16x8 a[4][2], b[4][2];

    const int NT = K >> 6;        // K-tiles of 64 (always even here)
    const int NI = NT >> 1;

    // ---- prologue: tile0 (buf0) full + tile1 (buf1) B-halves ----
    STG(As, pa, K,   0, 0, 0); STG(As, pa, K,   0, 1, 0);
    STG(Bs, pb, ldb, 0, 0, 0); STG(Bs, pb, ldb, 0, 1, 0);
    STG(Bs, pb, ldb, 1, 0, 1); STG(Bs, pb, ldb, 1, 1, 1);
    VMC4; BAR;

    // ---- main loop: 8 phases / iteration, 2 K-tiles / iteration ----
    // deadness: buf.B-halves die after p2/p6; buf.A-halves after p3/p7.
    // stages:  p1,p2 -> A of tile 2i+1 (buf1);  p3..p6 -> tile 2i+2 (buf0);
    //          p7,p8 -> B of tile 2i+3 (buf1).  vmcnt(4) at p4/p8 drains
    //          everything except the newest 2 half-tiles.
    for (int it = 0; it < NI; it++) {
        const int T1 = 2 * it + 1;
        int T2 = 2 * it + 2; if (T2 > NT - 1) T2 = NT - 1;   // clamp keeps
        int T3 = 2 * it + 3; if (T3 > NT - 1) T3 = NT - 1;   // vmcnt counts uniform
        // p1
        LDA4(0, 0); LDB2(0, 0);
        STG(As, pa, K, 1, 0, T1);
        BAR; PRIO1; MM(0, 0); PRIO0; BAR;
        // p2
        LDB2(0, 1);
        STG(As, pa, K, 1, 1, T1);
        BAR; PRIO1; MM(0, 1); PRIO0; BAR;
        // p3
        LDA4(0, 1);
        STG(Bs, pb, ldb, 0, 0, T2);
        BAR; PRIO1; MM(1, 1); PRIO0; BAR;
        // p4
        STG(Bs, pb, ldb, 0, 1, T2);
        BAR; PRIO1; MM(1, 0); PRIO0; VMC4; BAR;
        // p5
        LDA4(1, 0); LDB2(1, 0);
        STG(As, pa, K, 0, 0, T2);
        BAR; PRIO1; MM(0, 0); PRIO0; BAR;
        // p6
        LDB2(1, 1);
        STG(As, pa, K, 0, 1, T2);
        BAR; PRIO1; MM(0, 1); PRIO0; BAR;
        // p7
        LDA4(1, 1);
        STG(Bs, pb, ldb, 1, 0, T3);
        BAR; PRIO1; MM(1, 1); PRIO0; BAR;
        // p8
        STG(Bs, pb, ldb, 1, 1, T3);
        BAR; PRIO1; MM(1, 0); PRIO0; VMC4; BAR;
    }

    // ---- epilogue: D row = quad*4 + r (within 16-tile), col = lm ----
#pragma unroll
    for (int j = 0; j < 4; j++) {
        int col = n0 + wn * 64 + j * 16 + lm;
        u16* op;
        float bvl;
        size_t ldo;
        bool eluact = (MODE == 0);
        if (MODE == 4) {
            int seg = col >> 10;
            int c   = col & 1023;
            const float* bp = (seg == 0) ? bias : (seg == 1) ? biasK : biasV;
            u16* ob         = (seg == 0) ? out  : (seg == 1) ? outK  : outV;
            bvl = bp[c];
            op  = ob + c;
            ldo = 1024;
            eluact = (seg < 2);
        } else {
            bvl = (MODE == 5) ? 0.f : bias[col];
            op  = out + col;
            ldo = (size_t)N;
        }
#pragma unroll
        for (int i = 0; i < 8; i++) {
            int rbase = m0 + wm * 128 + i * 16 + quad * 4;
#pragma unroll
            for (int r = 0; r < 4; r++) {
                float z = acc[i][j][r] + bvl;
                float o;
                if (MODE == 1 || MODE == 5)      o = z;
                else if (MODE == 2)              o = gelu_f(gelu_f(z));
                else if (MODE == 3)              o = gelu_f(z);
                else if (MODE == 6)              o = gelu_f(z + bf2f(op[(size_t)(rbase + r) * ldo]));
                else                             o = eluact ? ((z > 0.f) ? z + 1.f : __expf(z)) : z;
                op[(size_t)(rbase + r) * ldo] = f2bf(o);
            }
        }
    }
}

// ---------------- KV / Ksum reduction over S (4 h per thread, ushort4) -------
__global__ __launch_bounds__(256) void kv_reduce(const u16* __restrict__ Kb,
                                                 const u16* __restrict__ vb,
                                                 float* __restrict__ KV,
                                                 float* __restrict__ Ks) {
    int n  = blockIdx.z;
    int h  = threadIdx.x * 4;          // A_ = 1024 = 256 threads * 4
    int s0 = blockIdx.y * 128;
    const u16* kp = Kb + (size_t)n * S_ * A_ + (size_t)s0 * A_ + h;
    const u16* vp = vb + (size_t)n * S_ * A_ + (size_t)s0 * A_ + h;
    float kv0 = 0.f, kv1 = 0.f, kv2 = 0.f, kv3 = 0.f;
    float ks0 = 0.f, ks1 = 0.f, ks2 = 0.f, ks3 = 0.f;
#pragma unroll 4
    for (int s = 0; s < 128; s++) {
        ushort4 k4 = *(const ushort4*)(kp + (size_t)s * A_);
        ushort4 v4 = *(const ushort4*)(vp + (size_t)s * A_);
        float k0 = bf2f(k4.x), k1 = bf2f(k4.y), k2 = bf2f(k4.z), k3 = bf2f(k4.w);
        kv0 += k0 * bf2f(v4.x); kv1 += k1 * bf2f(v4.y);
        kv2 += k2 * bf2f(v4.z); kv3 += k3 * bf2f(v4.w);
        ks0 += k0; ks1 += k1; ks2 += k2; ks3 += k3;
    }
    int base = n * A_ + h;
    atomicAdd(&KV[base + 0], kv0); atomicAdd(&KV[base + 1], kv1);
    atomicAdd(&KV[base + 2], kv2); atomicAdd(&KV[base + 3], kv3);
    atomicAdd(&Ks[base + 0], ks0); atomicAdd(&Ks[base + 1], ks1);
    atomicAdd(&Ks[base + 2], ks2); atomicAdd(&Ks[base + 3], ks3);
}

// ---------------- elementwise linear-attention output ------------------------
__global__ __launch_bounds__(256) void linattn_ew(const u16* __restrict__ Qb,
                                                  const float* __restrict__ KV,
                                                  const float* __restrict__ Ks,
                                                  u16* __restrict__ vout) {
    size_t idx = ((size_t)blockIdx.x * 256 + threadIdx.x) * 4;
    int n = (int)(idx >> 22);          // S_*A_ = 2^22
    int h = (int)(idx & (A_ - 1));
    ushort4 q4 = *(const ushort4*)(Qb + idx);
    int base = n * A_ + h;
    float4 kv4 = *(const float4*)(KV + base);
    float4 ks4 = *(const float4*)(Ks + base);
    float q0 = bf2f(q4.x), q1 = bf2f(q4.y), q2 = bf2f(q4.z), q3 = bf2f(q4.w);
    float o0 = q0 * kv4.x / (q0 * ks4.x + 1e-6f);
    float o1 = q1 * kv4.y / (q1 * ks4.y + 1e-6f);
    float o2 = q2 * kv4.z / (q2 * ks4.z + 1e-6f);
    float o3 = q3 * kv4.w / (q3 * ks4.w + 1e-6f);
    ushort4 o;
    o.x = f2bf(o0); o.y = f2bf(o1); o.z = f2bf(o2); o.w = f2bf(o3);
    *(ushort4*)(vout + idx) = o;
}

// ---------------- x init: f32 copy (residual) + bf16 cast --------------------
__global__ __launch_bounds__(256) void convert_x(const float* __restrict__ x,
                                                 float* __restrict__ xf,
                                                 u16* __restrict__ xb) {
    size_t idx = ((size_t)blockIdx.x * 256 + threadIdx.x) * 4;
    float4 v = *(const float4*)(x + idx);
    *(float4*)(xf + idx) = v;
    ushort4 o;
    o.x = f2bf(v.x); o.y = f2bf(v.y); o.z = f2bf(v.z); o.w = f2bf(v.w);
    *(ushort4*)(xb + idx) = o;
}

// ---------------- fused residual + LayerNorm (vectorized, shuffle reduce) ----
__global__ __launch_bounds__(256) void ln_fused(const u16* __restrict__ y,
                                                const float* __restrict__ res,
                                                const float* __restrict__ sc,
                                                const float* __restrict__ bs,
                                                float* __restrict__ xf,
                                                u16* __restrict__ xb) {
    __shared__ float wred[8];
    int row = blockIdx.x;
    int t   = threadIdx.x;
    int lane = t & 63, wid = t >> 6;
    const u16*   yp = y   + (size_t)row * D_;
    const float* rp = res + (size_t)row * D_;
    ushort4 y4 = *(const ushort4*)(yp + t * 4);
    float4  r4 = *(const float4*)(rp + t * 4);
    float v0 = bf2f(y4.x) + r4.x;
    float v1 = bf2f(y4.y) + r4.y;
    float v2 = bf2f(y4.z) + r4.z;
    float v3 = bf2f(y4.w) + r4.w;
    float s = v0 + v1 + v2 + v3;
#pragma unroll
    for (int o = 32; o; o >>= 1) s += __shfl_down(s, o, 64);
    if (lane == 0) wred[wid] = s;
    __syncthreads();
    float mean = (wred[0] + wred[1] + wred[2] + wred[3]) * (1.0f / D_);
    float d0 = v0 - mean, d1 = v1 - mean, d2 = v2 - mean, d3 = v3 - mean;
    float q = d0 * d0 + d1 * d1 + d2 * d2 + d3 * d3;
#pragma unroll
    for (int o = 32; o; o >>= 1) q += __shfl_down(q, o, 64);
    if (lane == 0) wred[wid + 4] = q;
    __syncthreads();
    float rstd = rsqrtf((wred[4] + wred[5] + wred[6] + wred[7]) * (1.0f / D_) + LN_EPS);
    float4 s4 = *(const float4*)(sc + t * 4);
    float4 b4 = *(const float4*)(bs + t * 4);
    float o0 = d0 * rstd * s4.x + b4.x;
    float o1 = d1 * rstd * s4.y + b4.y;
    float o2 = d2 * rstd * s4.z + b4.z;
    float o3 = d3 * rstd * s4.w + b4.w;
    *(float4*)(xf + (size_t)row * D_ + t * 4) = (float4){o0, o1, o2, o3};
    ushort4 ob;
    ob.x = f2bf(o0); ob.y = f2bf(o1); ob.z = f2bf(o2); ob.w = f2bf(o3);
    *(ushort4*)(xb + (size_t)row * D_ + t * 4) = ob;
}

extern "C" void kernel_launch(void* const* d_in, const int* in_sizes, int n_in,
                              void* d_out, int out_size, void* d_ws, size_t ws_size,
                              hipStream_t stream) {
    const float* x_in = (const float*)d_in[0];
    const float* Wq   = (const float*)d_in[1];
    const float* bq   = (const float*)d_in[2];
    const float* Wk   = (const float*)d_in[3];
    const float* bk   = (const float*)d_in[4];
    const float* Wv   = (const float*)d_in[5];
    const float* bv   = (const float*)d_in[6];
    const float* Wo   = (const float*)d_in[7];
    const float* bo   = (const float*)d_in[8];
    const float* ln1s = (const float*)d_in[9];
    const float* ln1b = (const float*)d_in[10];
    const float* W1   = (const float*)d_in[11];
    const float* b1   = (const float*)d_in[12];
    const float* W2   = (const float*)d_in[13];
    const float* b2   = (const float*)d_in[14];
    const float* ln2s = (const float*)d_in[15];
    const float* ln2b = (const float*)d_in[16];

    const size_t MB = 1024 * 1024;
    char* ws = (char*)d_ws;
    // Workspace layout: 153 MB total (<= 176 MB used previously).
    float* xf    = (float*)d_out;            // 64 MB fp32 residual / final out
    u16*   xb    = (u16*)(ws);               // 32 MB bf16 x (GEMM A)
    u16*   yb    = (u16*)(ws + 32 * MB);     // 32 MB bf16 v / a / FF-partial / f
    u16*   Qb    = (u16*)(ws + 64 * MB);     // 32 MB bf16 Q
    u16*   Kb    = (u16*)(ws + 96 * MB);     // 32 MB bf16 K, then Vattn
    u16*   hcb   = Qb;                       // 64 MB FF hidden half [16384][2048]
    u16*   WtQKV = (u16*)(ws + 128 * MB);    // 6 MB  [3072][1024] bf16
    u16*   Wot   = (u16*)(ws + 134 * MB);    // 2 MB
    u16*   W1t   = (u16*)(ws + 136 * MB);    // 8 MB  [4096][1024]
    u16*   W2t   = (u16*)(ws + 144 * MB);    // 8 MB  [1024][4096]
    float* kvb   = (float*)(ws + 152 * MB);  // 32 KB KV+Ksum
    float* KV    = kvb;
    float* Ks    = kvb + B_ * A_;

    const int M = B_ * S_;   // 16384

    convert_x<<<dim3(M * D_ / 1024), 256, 0, stream>>>(x_in, xf, xb);

    for (int i = 0; i < NB; i++) {
        const float* Wq_i = Wq + (size_t)i * D_ * A_;
        const float* Wk_i = Wk + (size_t)i * D_ * A_;
        const float* Wv_i = Wv + (size_t)i * D_ * A_;
        const float* Wo_i = Wo + (size_t)i * A_ * D_;
        const float* W1_i = W1 + (size_t)i * D_ * FF_;
        const float* W2_i = W2 + (size_t)i * FF_ * D_;

        // weight transposes (bf16 downcast) for this block
        transpose_w<<<dim3(A_ / 32, D_ / 32), dim3(32, 8), 0, stream>>>(Wq_i, WtQKV, D_, A_);
        transpose_w<<<dim3(A_ / 32, D_ / 32), dim3(32, 8), 0, stream>>>(Wk_i, WtQKV + (size_t)A_ * D_, D_, A_);
        transpose_w<<<dim3(A_ / 32, D_ / 32), dim3(32, 8), 0, stream>>>(Wv_i, WtQKV + (size_t)2 * A_ * D_, D_, A_);
        transpose_w<<<dim3(D_ / 32, A_ / 32), dim3(32, 8), 0, stream>>>(Wo_i, Wot, A_, D_);
        transpose_w<<<dim3(FF_ / 32, D_ / 32), dim3(32, 8), 0, stream>>>(W1_i, W1t, D_, FF_);
        transpose_w<<<dim3(D_ / 32, FF_ / 32), dim3(32, 8), 0, stream>>>(W2_i, W2t, FF_, D_);

        // fused QKV: [16384,1024] @ [1024,3072] -> Q(elu+1), K(elu+1), v(id)
        gemm256<4><<<dim3(12 * 64), 512, 0, stream>>>(
            xb, WtQKV, bq + i * A_, Qb, M, 3072, D_, 12, D_,
            Kb, yb, bk + i * A_, bv + i * A_);

        // KV[n,h] = sum_s K*v ; Ksum[n,h] = sum_s K
        zero_kv<<<dim3(8), 256, 0, stream>>>(kvb);
        kv_reduce<<<dim3(1, S_ / 128, B_), 256, 0, stream>>>(Kb, yb, KV, Ks);

        // Vattn = Q*KV / (Q*Ksum + 1e-6)  (overwrites Kb)
        linattn_ew<<<dim3(M * A_ / 1024), 256, 0, stream>>>(Qb, KV, Ks, Kb);

        // a = gelu(gelu(Vattn@Wo + bo))
        gemm256<2><<<dim3(4 * 64), 512, 0, stream>>>(
            Kb, Wot, bo + i * D_, yb, M, D_, A_, 4, A_,
            nullptr, nullptr, nullptr, nullptr);

        // x = LN(a + residual)
        ln_fused<<<dim3(M), 256, 0, stream>>>(yb, xf, ln1s + i * D_, ln1b + i * D_, xf, xb);

        // FF, chunked over the FF dimension (split-K for the 2nd GEMM):
        //   h_a = gelu(x@W1[:, :2048])          -> hcb   [16384][2048]
        //   P   = h_a @ W2[:2048, :]            -> yb    (bf16 partial, no bias)
        //   h_b = gelu(x@W1[:, 2048:])          -> hcb
        //   f   = gelu(P + h_b@W2[2048:,:] + b2)-> yb
        gemm256<3><<<dim3(8 * 64), 512, 0, stream>>>(
            xb, W1t, b1 + (size_t)i * FF_, hcb, M, 2048, D_, 8, D_,
            nullptr, nullptr, nullptr, nullptr);
        gemm256<5><<<dim3(4 * 64), 512, 0, stream>>>(
            hcb, W2t, b2 + i * D_, yb, M, D_, 2048, 4, FF_,
            nullptr, nullptr, nullptr, nullptr);
        gemm256<3><<<dim3(8 * 64), 512, 0, stream>>>(
            xb, W1t + (size_t)2048 * D_, b1 + (size_t)i * FF_ + 2048, hcb, M, 2048, D_, 8, D_,
            nullptr, nullptr, nullptr, nullptr);
        gemm256<6><<<dim3(4 * 64), 512, 0, stream>>>(
            hcb, W2t + 2048, b2 + i * D_, yb, M, D_, 2048, 4, FF_,
            nullptr, nullptr, nullptr, nullptr);

        // x = LN(f + residual)  (final block writes d_out via xf aliasing)
        ln_fused<<<dim3(M), 256, 0, stream>>>(yb, xf, ln2s + i * D_, ln2b + i * D_, xf, xb);
    }
}

// Round 2
// 2677.224 us; speedup vs baseline: 1.4985x; 1.2750x over previous
//
#include <hip/hip_runtime.h>
#include <hip/hip_bf16.h>

typedef unsigned short u16;

#define B_  4
#define S_  4096
#define D_  1024
#define A_  1024
#define FF_ 4096
#define NB  4
#define LN_EPS 1e-6f

typedef __bf16 bf16x8 __attribute__((ext_vector_type(8)));
typedef float  floatx4 __attribute__((ext_vector_type(4)));

__device__ __forceinline__ float gelu_f(float x) {
    // jax.nn.gelu approximate=True: 0.5x(1+tanh(u)) == x * sigmoid(2u)
    float u = 0.7978845608028654f * (x + 0.044715f * x * x * x);
    return x / (1.0f + __expf(-2.0f * u));
}

__device__ __forceinline__ u16 f2bf(float f) {
    __bf16 h = (__bf16)f;   // RNE convert
    return *(u16*)&h;
}

__device__ __forceinline__ float bf2f(u16 u) {
    unsigned int v = ((unsigned int)u) << 16;
    float f;
    __builtin_memcpy(&f, &v, 4);
    return f;
}

// async global->LDS 16B (direct-to-LDS DMA; dest = wave-uniform base + lane*16)
__device__ __forceinline__ void gload_lds16(const u16* g, u16* l) {
    __builtin_amdgcn_global_load_lds(
        (const __attribute__((address_space(1))) void*)g,
        (__attribute__((address_space(3))) void*)l, 16, 0, 0);
}

// ---------------- zero the KV/Ksum accumulators ------------------------------
__global__ __launch_bounds__(256) void zero_kv(float* __restrict__ p) {
    int idx = (blockIdx.x * 256 + threadIdx.x) * 4;   // 8 blocks -> 8192 floats
    *(float4*)(p + idx) = (float4){0.f, 0.f, 0.f, 0.f};
}

// ---------------- weight transpose + downcast: W[K,N] f32 -> Wt[N,K] bf16 ----
__global__ __launch_bounds__(256) void transpose_w(const float* __restrict__ W,
                                                   u16* __restrict__ Wt,
                                                   int K, int N) {
    __shared__ float tile[32][33];
    int tx = threadIdx.x;         // 0..31
    int ty = threadIdx.y;         // 0..7
    int n0 = blockIdx.x * 32;
    int k0 = blockIdx.y * 32;
#pragma unroll
    for (int r = 0; r < 4; r++) {
        int k = k0 + ty + r * 8;
        tile[ty + r * 8][tx] = W[(size_t)k * N + n0 + tx];
    }
    __syncthreads();
#pragma unroll
    for (int r = 0; r < 4; r++) {
        int n = n0 + ty + r * 8;
        Wt[(size_t)n * K + k0 + tx] = f2bf(tile[tx][ty + r * 8]);
    }
}

// =============================================================================
// 256x256 8-phase bf16 MFMA GEMM (m201-style template, plain HIP).
//   C[M,N] = act(A[M,K] @ Bt[N,K]^T + bias)      (lda = ldb = K)
// 8 waves (2Mx4N), BK=64, 128KB LDS double-buffer, XOR slot-swizzle
// (linear global_load_lds dest + inverse-swizzled global src + swizzled read),
// counted vmcnt(4) at phases 4/8 only, setprio(1) around MFMA clusters,
// bijective XCD swizzle (all grids % 8 == 0).
// Epilogue: drain DMA, restage C tile into LDS [256][264] bf16 (padded rows),
// then fully-coalesced dwordx4 stores (one 256B row-half per thread) -> no
// partial-line RMW traffic.
// MODE: 2=gelu(gelu)  3=gelu  4=QKV scatter (seg0/1->elu+1; seg2->identity)
// =============================================================================
#define BAR  { asm volatile("" ::: "memory"); __builtin_amdgcn_s_barrier(); \
               asm volatile("" ::: "memory"); }
#define VMC4 asm volatile("s_waitcnt vmcnt(4)" ::: "memory")
#define PRIO1 __builtin_amdgcn_s_setprio(1)
#define PRIO0 __builtin_amdgcn_s_setprio(0)

#define STG(BASE, P, LD, BUF, H, KT) {                                         \
    const u16* s_ = (P) + (size_t)((H) * 128) * (LD) + (KT) * 64;              \
    u16* d_ = (BASE) + (BUF) * 16384 + (H) * 8192 + t * 8;                     \
    gload_lds16(s_, d_);                                                       \
    gload_lds16(s_ + (size_t)64 * (LD), d_ + 4096); }

#define LDA4(BUF, IH) {                                                        \
    _Pragma("unroll") for (int ii = 0; ii < 4; ii++) {                         \
        const u16* p_ = As0 + (BUF) * 16384 + aro + ((IH) * 4 + ii) * 1024;    \
        a[ii][0] = *(const bf16x8*)(p_ + sl0);                                 \
        a[ii][1] = *(const bf16x8*)(p_ + sl1); } }

#define LDB2(BUF, JH) {                                                        \
    _Pragma("unroll") for (int jj = 0; jj < 2; jj++) {                         \
        const u16* p_ = Bs0 + (BUF) * 16384 + bro + ((JH) * 2 + jj) * 1024;    \
        b[(JH) * 2 + jj][0] = *(const bf16x8*)(p_ + sl0);                      \
        b[(JH) * 2 + jj][1] = *(const bf16x8*)(p_ + sl1); } }

#define MM(IH, JH) {                                                           \
    _Pragma("unroll") for (int ii = 0; ii < 4; ii++)                           \
    _Pragma("unroll") for (int jj = 0; jj < 2; jj++)                           \
    _Pragma("unroll") for (int s = 0; s < 2; s++)                              \
        acc[(IH) * 4 + ii][(JH) * 2 + jj] =                                    \
            __builtin_amdgcn_mfma_f32_16x16x32_bf16(                           \
                a[ii][s], b[(JH) * 2 + jj][s],                                 \
                acc[(IH) * 4 + ii][(JH) * 2 + jj], 0, 0, 0); }

template <int MODE>
__global__ __launch_bounds__(512, 2) void gemm256(
    const u16* __restrict__ Amat, const u16* __restrict__ Bt,
    const float* __restrict__ bias, u16* __restrict__ out,
    int M, int N, int K, int gx, int ldo,
    u16* __restrict__ outK, u16* __restrict__ outV,
    const float* __restrict__ biasK, const float* __restrict__ biasV)
{
    // 135168 B: main loop uses first 131072 as As[2]/Bs[2]; epilogue reuses all
    // of it as a padded [256][264] bf16 C tile.
    __shared__ u16 shm[67584];
    u16* As0 = shm;            // As[buf] = As0 + buf*16384
    u16* Bs0 = shm + 32768;    // Bs[buf] = Bs0 + buf*16384

    // bijective XCD swizzle (grid is a multiple of 8 for all launches)
    const int nwg  = (int)gridDim.x;
    const int cpx  = nwg >> 3;
    const int wgid = ((int)blockIdx.x & 7) * cpx + ((int)blockIdx.x >> 3);
    const int bx = wgid % gx;
    const int by = wgid / gx;
    const int m0 = by * 256, n0 = bx * 256;

    const int t    = threadIdx.x;
    const int wid  = t >> 6, lane = t & 63;
    const int wm   = wid >> 2, wn = wid & 3;   // 2 x 4 waves
    const int lm   = lane & 15, quad = lane >> 4;

    // staging source (per-lane): row trow(+h*128+64u); 16B slot inverse-swizzled
    const int trow  = t >> 3;
    const int tslot = (t & 7) ^ (trow & 7);
    const u16* pa = Amat + (size_t)(m0 + trow) * K + tslot * 8;
    const u16* pb = Bt   + (size_t)(n0 + trow) * K + tslot * 8;

    // LDS fragment-read bases (shorts); slot XOR makes reads bank-uniform
    const int aro = (wm * 128 + lm) * 64;
    const int bro = (wn * 64  + lm) * 64;
    const int sl0 = ((0 * 4 + quad) ^ (lm & 7)) * 8;
    const int sl1 = ((1 * 4 + quad) ^ (lm & 7)) * 8;

    floatx4 acc[8][4];
#pragma unroll
    for (int i = 0; i < 8; i++)
#pragma unroll
        for (int j = 0; j < 4; j++) acc[i][j] = (floatx4){0.f, 0.f, 0.f, 0.f};

    bf16x8 a[4][2], b[4][2];

    const int NT = K >> 6;        // K-tiles of 64 (always even here)
    const int NI = NT >> 1;

    // ---- prologue: tile0 (buf0) full + tile1 (buf1) B-halves ----
    STG(As0, pa, K, 0, 0, 0); STG(As0, pa, K, 0, 1, 0);
    STG(Bs0, pb, K, 0, 0, 0); STG(Bs0, pb, K, 0, 1, 0);
    STG(Bs0, pb, K, 1, 0, 1); STG(Bs0, pb, K, 1, 1, 1);
    VMC4; BAR;

    // ---- main loop: 8 phases / iteration, 2 K-tiles / iteration ----
    for (int it = 0; it < NI; it++) {
        const int T1 = 2 * it + 1;
        int T2 = 2 * it + 2; if (T2 > NT - 1) T2 = NT - 1;   // clamp keeps
        int T3 = 2 * it + 3; if (T3 > NT - 1) T3 = NT - 1;   // vmcnt counts uniform
        // p1
        LDA4(0, 0); LDB2(0, 0);
        STG(As0, pa, K, 1, 0, T1);
        BAR; PRIO1; MM(0, 0); PRIO0; BAR;
        // p2
        LDB2(0, 1);
        STG(As0, pa, K, 1, 1, T1);
        BAR; PRIO1; MM(0, 1); PRIO0; BAR;
        // p3
        LDA4(0, 1);
        STG(Bs0, pb, K, 0, 0, T2);
        BAR; PRIO1; MM(1, 1); PRIO0; BAR;
        // p4
        STG(Bs0, pb, K, 0, 1, T2);
        BAR; PRIO1; MM(1, 0); PRIO0; VMC4; BAR;
        // p5
        LDA4(1, 0); LDB2(1, 0);
        STG(As0, pa, K, 0, 0, T2);
        BAR; PRIO1; MM(0, 0); PRIO0; BAR;
        // p6
        LDB2(1, 1);
        STG(As0, pa, K, 0, 1, T2);
        BAR; PRIO1; MM(0, 1); PRIO0; BAR;
        // p7
        LDA4(1, 1);
        STG(Bs0, pb, K, 1, 0, T3);
        BAR; PRIO1; MM(1, 1); PRIO0; BAR;
        // p8
        STG(Bs0, pb, K, 1, 1, T3);
        BAR; PRIO1; MM(1, 0); PRIO0; VMC4; BAR;
    }

    // ---- epilogue ----
    // Drain in-flight DMA (it targets As/Bs = our C staging area), then barrier
    // so no wave's pending global_load_lds can land after restaging begins.
    asm volatile("s_waitcnt vmcnt(0)" ::: "memory");
    __syncthreads();

    // per-block-uniform output mapping (QKV tiles never straddle segments)
    const float* bp; u16* ob; int c0; bool elu;
    if (MODE == 4) {
        int seg = n0 >> 10;
        bp  = (seg == 0) ? bias : (seg == 1) ? biasK : biasV;
        ob  = (seg == 0) ? out  : (seg == 1) ? outK  : outV;
        c0  = n0 & 1023;
        elu = (seg < 2);
    } else { bp = bias; ob = out; c0 = n0; elu = false; }

    u16* Ct = shm;   // [256][264] bf16, 16B-aligned rows (528B stride)
#pragma unroll
    for (int j = 0; j < 4; j++) {
        int cl   = wn * 64 + j * 16 + lm;
        float bvl = bp[c0 + cl];
#pragma unroll
        for (int i = 0; i < 8; i++) {
            int rl = wm * 128 + i * 16 + quad * 4;
#pragma unroll
            for (int r = 0; r < 4; r++) {
                float z = acc[i][j][r] + bvl;
                float o;
                if (MODE == 2)      o = gelu_f(gelu_f(z));
                else if (MODE == 3) o = gelu_f(z);
                else if (MODE == 4) o = elu ? ((z > 0.f) ? z + 1.f : __expf(z)) : z;
                else                o = z;
                Ct[(rl + r) * 264 + cl] = f2bf(o);
            }
        }
    }
    __syncthreads();

    // coalesced stores: thread t -> row t>>1, col-half (t&1)*128; 16x dwordx4
    {
        int row = t >> 1;
        int ch  = (t & 1) * 128;
        const u16* src = Ct + row * 264 + ch;
        u16* dst = ob + (size_t)(m0 + row) * ldo + c0 + ch;
#pragma unroll
        for (int cc = 0; cc < 128; cc += 8)
            *(uint4*)(dst + cc) = *(const uint4*)(src + cc);
    }
}

// ---------------- KV / Ksum reduction over S (4 h per thread, ushort4) -------
__global__ __launch_bounds__(256) void kv_reduce(const u16* __restrict__ Kb,
                                                 const u16* __restrict__ vb,
                                                 float* __restrict__ KV,
                                                 float* __restrict__ Ks) {
    int n  = blockIdx.z;
    int h  = threadIdx.x * 4;          // A_ = 1024 = 256 threads * 4
    int s0 = blockIdx.y * 128;
    const u16* kp = Kb + (size_t)n * S_ * A_ + (size_t)s0 * A_ + h;
    const u16* vp = vb + (size_t)n * S_ * A_ + (size_t)s0 * A_ + h;
    float kv0 = 0.f, kv1 = 0.f, kv2 = 0.f, kv3 = 0.f;
    float ks0 = 0.f, ks1 = 0.f, ks2 = 0.f, ks3 = 0.f;
#pragma unroll 4
    for (int s = 0; s < 128; s++) {
        ushort4 k4 = *(const ushort4*)(kp + (size_t)s * A_);
        ushort4 v4 = *(const ushort4*)(vp + (size_t)s * A_);
        float k0 = bf2f(k4.x), k1 = bf2f(k4.y), k2 = bf2f(k4.z), k3 = bf2f(k4.w);
        kv0 += k0 * bf2f(v4.x); kv1 += k1 * bf2f(v4.y);
        kv2 += k2 * bf2f(v4.z); kv3 += k3 * bf2f(v4.w);
        ks0 += k0; ks1 += k1; ks2 += k2; ks3 += k3;
    }
    int base = n * A_ + h;
    atomicAdd(&KV[base + 0], kv0); atomicAdd(&KV[base + 1], kv1);
    atomicAdd(&KV[base + 2], kv2); atomicAdd(&KV[base + 3], kv3);
    atomicAdd(&Ks[base + 0], ks0); atomicAdd(&Ks[base + 1], ks1);
    atomicAdd(&Ks[base + 2], ks2); atomicAdd(&Ks[base + 3], ks3);
}

// ---------------- elementwise linear-attention output ------------------------
__global__ __launch_bounds__(256) void linattn_ew(const u16* __restrict__ Qb,
                                                  const float* __restrict__ KV,
                                                  const float* __restrict__ Ks,
                                                  u16* __restrict__ vout) {
    size_t idx = ((size_t)blockIdx.x * 256 + threadIdx.x) * 4;
    int n = (int)(idx >> 22);          // S_*A_ = 2^22
    int h = (int)(idx & (A_ - 1));
    ushort4 q4 = *(const ushort4*)(Qb + idx);
    int base = n * A_ + h;
    float4 kv4 = *(const float4*)(KV + base);
    float4 ks4 = *(const float4*)(Ks + base);
    float q0 = bf2f(q4.x), q1 = bf2f(q4.y), q2 = bf2f(q4.z), q3 = bf2f(q4.w);
    float o0 = q0 * kv4.x / (q0 * ks4.x + 1e-6f);
    float o1 = q1 * kv4.y / (q1 * ks4.y + 1e-6f);
    float o2 = q2 * kv4.z / (q2 * ks4.z + 1e-6f);
    float o3 = q3 * kv4.w / (q3 * ks4.w + 1e-6f);
    ushort4 o;
    o.x = f2bf(o0); o.y = f2bf(o1); o.z = f2bf(o2); o.w = f2bf(o3);
    *(ushort4*)(vout + idx) = o;
}

// ---------------- x init: f32 copy (residual) + bf16 cast --------------------
__global__ __launch_bounds__(256) void convert_x(const float* __restrict__ x,
                                                 float* __restrict__ xf,
                                                 u16* __restrict__ xb) {
    size_t idx = ((size_t)blockIdx.x * 256 + threadIdx.x) * 4;
    float4 v = *(const float4*)(x + idx);
    *(float4*)(xf + idx) = v;
    ushort4 o;
    o.x = f2bf(v.x); o.y = f2bf(v.y); o.z = f2bf(v.z); o.w = f2bf(v.w);
    *(ushort4*)(xb + idx) = o;
}

// ---------------- fused residual + LayerNorm (vectorized, shuffle reduce) ----
// NOTE: y/xb and res/xf may alias (in-place); each thread reads its elements
// before the first barrier and writes them only after the second -> safe.
__global__ __launch_bounds__(256) void ln_fused(const u16* y,
                                                const float* res,
                                                const float* sc,
                                                const float* bs,
                                                float* xf,
                                                u16* xb) {
    __shared__ float wred[8];
    int row = blockIdx.x;
    int t   = threadIdx.x;
    int lane = t & 63, wid = t >> 6;
    const u16*   yp = y   + (size_t)row * D_;
    const float* rp = res + (size_t)row * D_;
    ushort4 y4 = *(const ushort4*)(yp + t * 4);
    float4  r4 = *(const float4*)(rp + t * 4);
    float v0 = bf2f(y4.x) + r4.x;
    float v1 = bf2f(y4.y) + r4.y;
    float v2 = bf2f(y4.z) + r4.z;
    float v3 = bf2f(y4.w) + r4.w;
    float s = v0 + v1 + v2 + v3;
#pragma unroll
    for (int o = 32; o; o >>= 1) s += __shfl_down(s, o, 64);
    if (lane == 0) wred[wid] = s;
    __syncthreads();
    float mean = (wred[0] + wred[1] + wred[2] + wred[3]) * (1.0f / D_);
    float d0 = v0 - mean, d1 = v1 - mean, d2 = v2 - mean, d3 = v3 - mean;
    float q = d0 * d0 + d1 * d1 + d2 * d2 + d3 * d3;
#pragma unroll
    for (int o = 32; o; o >>= 1) q += __shfl_down(q, o, 64);
    if (lane == 0) wred[wid + 4] = q;
    __syncthreads();
    float rstd = rsqrtf((wred[4] + wred[5] + wred[6] + wred[7]) * (1.0f / D_) + LN_EPS);
    float4 s4 = *(const float4*)(sc + t * 4);
    float4 b4 = *(const float4*)(bs + t * 4);
    float o0 = d0 * rstd * s4.x + b4.x;
    float o1 = d1 * rstd * s4.y + b4.y;
    float o2 = d2 * rstd * s4.z + b4.z;
    float o3 = d3 * rstd * s4.w + b4.w;
    *(float4*)(xf + (size_t)row * D_ + t * 4) = (float4){o0, o1, o2, o3};
    ushort4 ob;
    ob.x = f2bf(o0); ob.y = f2bf(o1); ob.z = f2bf(o2); ob.w = f2bf(o3);
    *(ushort4*)(xb + (size_t)row * D_ + t * 4) = ob;
}

extern "C" void kernel_launch(void* const* d_in, const int* in_sizes, int n_in,
                              void* d_out, int out_size, void* d_ws, size_t ws_size,
                              hipStream_t stream) {
    const float* x_in = (const float*)d_in[0];
    const float* Wq   = (const float*)d_in[1];
    const float* bq   = (const float*)d_in[2];
    const float* Wk   = (const float*)d_in[3];
    const float* bk   = (const float*)d_in[4];
    const float* Wv   = (const float*)d_in[5];
    const float* bv   = (const float*)d_in[6];
    const float* Wo   = (const float*)d_in[7];
    const float* bo   = (const float*)d_in[8];
    const float* ln1s = (const float*)d_in[9];
    const float* ln1b = (const float*)d_in[10];
    const float* W1   = (const float*)d_in[11];
    const float* b1   = (const float*)d_in[12];
    const float* W2   = (const float*)d_in[13];
    const float* b2   = (const float*)d_in[14];
    const float* ln2s = (const float*)d_in[15];
    const float* ln2b = (const float*)d_in[16];

    const size_t MB = 1024 * 1024;
    char* ws = (char*)d_ws;
    // Workspace layout: 176 MB total.
    //   0- 32 : xb   bf16 x (GEMM A); FF2 writes f here in-place
    //  32- 64 : Qb   bf16 Q                      } dead by FF time ->
    //  64- 96 : Kb   bf16 K, then Vattn          }  overlaid by
    //  96-128 : vb   bf16 v, then a (Wo output)  }  hidden [16384][4096]
    // 128-134 : WtQKV bf16 [3072][1024]          }  (128 MB @ 32..160)
    // 134-136 : Wot  bf16 [1024][1024]           }
    // 136-...: kvb  KV+Ksum 32 KB                }
    // 160-168 : W1t  bf16 [4096][1024]   (live through FF)
    // 168-176 : W2t  bf16 [1024][4096]   (live through FF)
    float* xf    = (float*)d_out;            // 64 MB fp32 residual / final out
    u16*   xb    = (u16*)(ws);
    u16*   Qb    = (u16*)(ws + 32 * MB);
    u16*   Kb    = (u16*)(ws + 64 * MB);
    u16*   vb    = (u16*)(ws + 96 * MB);
    u16*   hid   = (u16*)(ws + 32 * MB);     // [16384][4096] bf16, 128 MB
    u16*   WtQKV = (u16*)(ws + 128 * MB);
    u16*   Wot   = (u16*)(ws + 134 * MB);
    float* kvb   = (float*)(ws + 136 * MB);
    u16*   W1t   = (u16*)(ws + 160 * MB);
    u16*   W2t   = (u16*)(ws + 168 * MB);
    float* KV    = kvb;
    float* Ks    = kvb + B_ * A_;

    const int M = B_ * S_;   // 16384

    convert_x<<<dim3(M * D_ / 1024), 256, 0, stream>>>(x_in, xf, xb);

    for (int i = 0; i < NB; i++) {
        const float* Wq_i = Wq + (size_t)i * D_ * A_;
        const float* Wk_i = Wk + (size_t)i * D_ * A_;
        const float* Wv_i = Wv + (size_t)i * D_ * A_;
        const float* Wo_i = Wo + (size_t)i * A_ * D_;
        const float* W1_i = W1 + (size_t)i * D_ * FF_;
        const float* W2_i = W2 + (size_t)i * FF_ * D_;

        // weight transposes (bf16 downcast) for this block
        transpose_w<<<dim3(A_ / 32, D_ / 32), dim3(32, 8), 0, stream>>>(Wq_i, WtQKV, D_, A_);
        transpose_w<<<dim3(A_ / 32, D_ / 32), dim3(32, 8), 0, stream>>>(Wk_i, WtQKV + (size_t)A_ * D_, D_, A_);
        transpose_w<<<dim3(A_ / 32, D_ / 32), dim3(32, 8), 0, stream>>>(Wv_i, WtQKV + (size_t)2 * A_ * D_, D_, A_);
        transpose_w<<<dim3(D_ / 32, A_ / 32), dim3(32, 8), 0, stream>>>(Wo_i, Wot, A_, D_);
        transpose_w<<<dim3(FF_ / 32, D_ / 32), dim3(32, 8), 0, stream>>>(W1_i, W1t, D_, FF_);
        transpose_w<<<dim3(D_ / 32, FF_ / 32), dim3(32, 8), 0, stream>>>(W2_i, W2t, FF_, D_);

        // fused QKV: [16384,1024] @ [1024,3072] -> Q(elu+1), K(elu+1), v(id)
        gemm256<4><<<dim3(12 * 64), 512, 0, stream>>>(
            xb, WtQKV, bq + i * A_, Qb, M, 3072, D_, 12, 1024,
            Kb, vb, bk + i * A_, bv + i * A_);

        // KV[n,h] = sum_s K*v ; Ksum[n,h] = sum_s K
        zero_kv<<<dim3(8), 256, 0, stream>>>(kvb);
        kv_reduce<<<dim3(1, S_ / 128, B_), 256, 0, stream>>>(Kb, vb, KV, Ks);

        // Vattn = Q*KV / (Q*Ksum + 1e-6)  (overwrites Kb)
        linattn_ew<<<dim3(M * A_ / 1024), 256, 0, stream>>>(Qb, KV, Ks, Kb);

        // a = gelu(gelu(Vattn@Wo + bo)) -> vb
        gemm256<2><<<dim3(4 * 64), 512, 0, stream>>>(
            Kb, Wot, bo + i * D_, vb, M, D_, A_, 4, 1024,
            nullptr, nullptr, nullptr, nullptr);

        // x = LN(a + residual)
        ln_fused<<<dim3(M), 256, 0, stream>>>(vb, xf, ln1s + i * D_, ln1b + i * D_, xf, xb);

        // FF (no split-K): h = gelu(x@W1+b1) full [16384][4096]; f = gelu(h@W2+b2)
        gemm256<3><<<dim3(16 * 64), 512, 0, stream>>>(
            xb, W1t, b1 + (size_t)i * FF_, hid, M, FF_, D_, 16, 4096,
            nullptr, nullptr, nullptr, nullptr);
        gemm256<3><<<dim3(4 * 64), 512, 0, stream>>>(
            hid, W2t, b2 + i * D_, xb, M, D_, FF_, 4, 1024,
            nullptr, nullptr, nullptr, nullptr);

        // x = LN(f + residual)  (xb in-place; final block writes d_out via xf)
        ln_fused<<<dim3(M), 256, 0, stream>>>(xb, xf, ln2s + i * D_, ln2b + i * D_, xf, xb);
    }
}

// Round 3
// 2606.316 us; speedup vs baseline: 1.5393x; 1.0272x over previous
//
#include <hip/hip_runtime.h>
#include <hip/hip_bf16.h>

typedef unsigned short u16;

#define B_  4
#define S_  4096
#define D_  1024
#define A_  1024
#define FF_ 4096
#define NB  4
#define LN_EPS 1e-6f

typedef __bf16 bf16x8 __attribute__((ext_vector_type(8)));
typedef float  floatx4 __attribute__((ext_vector_type(4)));

__device__ __forceinline__ float gelu_f(float x) {
    // jax.nn.gelu approximate=True: 0.5x(1+tanh(u)) == x * sigmoid(2u)
    float u = 0.7978845608028654f * (x + 0.044715f * x * x * x);
    return x / (1.0f + __expf(-2.0f * u));
}

__device__ __forceinline__ u16 f2bf(float f) {
    __bf16 h = (__bf16)f;   // RNE convert
    return *(u16*)&h;
}

__device__ __forceinline__ float bf2f(u16 u) {
    unsigned int v = ((unsigned int)u) << 16;
    float f;
    __builtin_memcpy(&f, &v, 4);
    return f;
}

// async global->LDS 16B (direct-to-LDS DMA; dest = wave-uniform base + lane*16)
__device__ __forceinline__ void gload_lds16(const u16* g, u16* l) {
    __builtin_amdgcn_global_load_lds(
        (const __attribute__((address_space(1))) void*)g,
        (__attribute__((address_space(3))) void*)l, 16, 0, 0);
}

// ---------------- zero the KV/Ksum accumulators ------------------------------
__global__ __launch_bounds__(256) void zero_kv(float* __restrict__ p) {
    int idx = (blockIdx.x * 256 + threadIdx.x) * 4;   // 8 blocks -> 8192 floats
    *(float4*)(p + idx) = (float4){0.f, 0.f, 0.f, 0.f};
}

// ---------------- weight transpose + downcast: W[K,N] f32 -> Wt[N,K] bf16 ----
__global__ __launch_bounds__(256) void transpose_w(const float* __restrict__ W,
                                                   u16* __restrict__ Wt,
                                                   int K, int N) {
    __shared__ float tile[32][33];
    int tx = threadIdx.x;         // 0..31
    int ty = threadIdx.y;         // 0..7
    int n0 = blockIdx.x * 32;
    int k0 = blockIdx.y * 32;
#pragma unroll
    for (int r = 0; r < 4; r++) {
        int k = k0 + ty + r * 8;
        tile[ty + r * 8][tx] = W[(size_t)k * N + n0 + tx];
    }
    __syncthreads();
#pragma unroll
    for (int r = 0; r < 4; r++) {
        int n = n0 + ty + r * 8;
        Wt[(size_t)n * K + k0 + tx] = f2bf(tile[tx][ty + r * 8]);
    }
}

// =============================================================================
// 256x256 bf16 MFMA GEMM, per-tile 4-phase pipeline.
//   C[M,N] = act(A[M,K] @ Bt[N,K]^T + bias)      (lda = ldb = K)
// 8 waves (2Mx4N), BK=64. LDS 160KB: A double-buffer (2x32KB) + B TRIPLE
// buffer (3x32KB) -> B prefetch lead ~2 tiles (~7 phases) to cover L2-miss
// latency on weights; uniform vmcnt(2) once per tile (P2).
// Cluster re-split for LDS/MFMA overlap: each phase runs a 2-rowpair x 4j x 2s
// cluster (16 MFMA) whose fragments were ds_read one phase EARLIER, so the
// LDS pipe streams the next cluster's operands while the matrix pipe runs.
// Next tile's b[8]+pair0 reads issue at P3 (their data was vmcnt-forced at P2
// and barrier-published) -> every cluster has >=1 phase of read slack.
// XOR slot-swizzle (linear DMA dest + inverse-swizzled global src + swizzled
// read) keeps ds_read_b128 bank-conflict-free. Bijective XCD swizzle.
// Epilogue: drain DMA, restage C into LDS [256][264] bf16, coalesced dwordx4.
// MODE: 2=gelu(gelu)  3=gelu  4=QKV scatter (seg0/1->elu+1; seg2->identity)
// =============================================================================
#define BAR  { asm volatile("" ::: "memory"); __builtin_amdgcn_s_barrier(); \
               asm volatile("" ::: "memory"); }
#define VMC(N) asm volatile("s_waitcnt vmcnt(" #N ")" ::: "memory")
#define PRIO1 __builtin_amdgcn_s_setprio(1)
#define PRIO0 __builtin_amdgcn_s_setprio(0)

// stage one 128-row half-tile (2 x 16B DMA per thread) into shm+OFF
#define STG(OFF, P, LD, H, KT) {                                               \
    const u16* s_ = (P) + (size_t)((H) * 128) * (LD) + (KT) * 64;              \
    u16* d_ = shm + (OFF) + (H) * 8192 + t * 8;                                \
    gload_lds16(s_, d_);                                                       \
    gload_lds16(s_ + (size_t)64 * (LD), d_ + 4096); }

// read one a row-pair (4 x ds_read_b128) into slot SL
#define LDA2(AOFF, PAIR, SL) {                                                 \
    _Pragma("unroll") for (int ii = 0; ii < 2; ii++) {                         \
        const u16* p_ = shm + (AOFF) + aro + ((PAIR) * 2 + ii) * 1024;         \
        a[SL][ii][0] = *(const bf16x8*)(p_ + sl0);                             \
        a[SL][ii][1] = *(const bf16x8*)(p_ + sl1); } }

// read the full b set for a tile (8 x ds_read_b128)
#define LDBALL(BOFF) {                                                         \
    _Pragma("unroll") for (int jj = 0; jj < 4; jj++) {                         \
        const u16* p_ = shm + (BOFF) + bro + jj * 1024;                        \
        b[jj][0] = *(const bf16x8*)(p_ + sl0);                                 \
        b[jj][1] = *(const bf16x8*)(p_ + sl1); } }

// cluster C: rows {2C,2C+1} x all 4 j x 2 k-slots = 16 MFMA, operands slot SL
#define MMC(SL, C) {                                                           \
    _Pragma("unroll") for (int ii = 0; ii < 2; ii++)                           \
    _Pragma("unroll") for (int jj = 0; jj < 4; jj++)                           \
    _Pragma("unroll") for (int s = 0; s < 2; s++)                              \
        acc[(C) * 2 + ii][jj] = __builtin_amdgcn_mfma_f32_16x16x32_bf16(       \
            a[SL][ii][s], b[jj][s], acc[(C) * 2 + ii][jj], 0, 0, 0); }

template <int MODE>
__global__ __launch_bounds__(512, 2) void gemm256(
    const u16* __restrict__ Amat, const u16* __restrict__ Bt,
    const float* __restrict__ bias, u16* __restrict__ out,
    int M, int N, int K, int gx, int ldo,
    u16* __restrict__ outK, u16* __restrict__ outV,
    const float* __restrict__ biasK, const float* __restrict__ biasV)
{
    // 160 KB: A bufs @ 0,16384; B bufs @ 32768,49152,65536 (u16 offsets).
    // Epilogue reuses the first 135168 B as a padded [256][264] bf16 C tile.
    __shared__ u16 shm[81920];

    // bijective XCD swizzle (grid is a multiple of 8 for all launches)
    const int nwg  = (int)gridDim.x;
    const int cpx  = nwg >> 3;
    const int wgid = ((int)blockIdx.x & 7) * cpx + ((int)blockIdx.x >> 3);
    const int bx = wgid % gx;
    const int by = wgid / gx;
    const int m0 = by * 256, n0 = bx * 256;

    const int t    = threadIdx.x;
    const int wid  = t >> 6, lane = t & 63;
    const int wm   = wid >> 2, wn = wid & 3;   // 2 x 4 waves
    const int lm   = lane & 15, quad = lane >> 4;

    // staging source (per-lane): row trow(+h*128+64u); 16B slot inverse-swizzled
    const int trow  = t >> 3;
    const int tslot = (t & 7) ^ (trow & 7);
    const u16* pa = Amat + (size_t)(m0 + trow) * K + tslot * 8;
    const u16* pb = Bt   + (size_t)(n0 + trow) * K + tslot * 8;

    // LDS fragment-read bases (u16 units); slot XOR makes reads bank-uniform
    const int aro = (wm * 128 + lm) * 64;
    const int bro = (wn * 64  + lm) * 64;
    const int sl0 = ((0 * 4 + quad) ^ (lm & 7)) * 8;
    const int sl1 = ((1 * 4 + quad) ^ (lm & 7)) * 8;

    floatx4 acc[8][4];
#pragma unroll
    for (int i = 0; i < 8; i++)
#pragma unroll
        for (int j = 0; j < 4; j++) acc[i][j] = (floatx4){0.f, 0.f, 0.f, 0.f};

    bf16x8 a[2][2][2];   // [slot][rowpair-half][k-slot]
    bf16x8 b[4][2];

    int aCur = 0,      aNxt = 16384;
    int bCur = 32768,  bNx1 = 49152, bNx2 = 65536;

    const int NT = K >> 6;        // K-tiles of 64 (NT >= 16 here)

    // ---- prologue: A(0)->aCur, B(0)->bCur, B(1)->bNx1; force A0,B0 ----
    STG(aCur, pa, K, 0, 0); STG(aCur, pa, K, 1, 0);
    STG(bCur, pb, K, 0, 0); STG(bCur, pb, K, 1, 0);
    STG(bNx1, pb, K, 0, 1); STG(bNx1, pb, K, 1, 1);
    VMC(4);          // 12 issued, leave bNx1's 4 in flight
    BAR;
    LDBALL(bCur);    // tile-0 b set
    LDA2(aCur, 0, 0);// tile-0 rowpair 0 -> slot 0

    // ---- main loop: 4 phases per K-tile ----
    // stages: P0/P1 -> A(t+1) into aNxt; P2/P3 -> B(t+2) into bNx2.
    // vmcnt(2) at P2 forces B(t+1) and A(t+1) (leaves B(t+2) H0 in flight);
    // P3 (after the barrier) may then read next tile's b + pair0.
    for (int tt = 0; tt < NT; tt++) {
        int t1 = tt + 1; if (t1 > NT - 1) t1 = NT - 1;   // clamped dummy stages
        int t2 = tt + 2; if (t2 > NT - 1) t2 = NT - 1;   // keep vmcnt uniform
        // P0
        LDA2(aCur, 1, 1);
        STG(aNxt, pa, K, 0, t1);
        BAR; PRIO1; MMC(0, 0); PRIO0; BAR;
        // P1
        LDA2(aCur, 2, 0);
        STG(aNxt, pa, K, 1, t1);
        BAR; PRIO1; MMC(1, 1); PRIO0; BAR;
        // P2
        LDA2(aCur, 3, 1);
        STG(bNx2, pb, K, 0, t2);
        BAR; PRIO1; MMC(0, 2); PRIO0;
        VMC(2);
        BAR;
        // P3  (reads for tile tt+1: data forced at P2 + published by its BAR)
        STG(bNx2, pb, K, 1, t2);
        BAR; PRIO1; MMC(1, 3); PRIO0;
        LDBALL(bNx1);
        LDA2(aNxt, 0, 0);
        BAR;
        // rotate buffers
        int tmp = aCur; aCur = aNxt; aNxt = tmp;
        tmp = bCur; bCur = bNx1; bNx1 = bNx2; bNx2 = tmp;
    }

    // ---- epilogue ----
    // Drain in-flight DMA (it targets the staging buffers = our C staging
    // area), then barrier so no pending DMA lands after restaging begins.
    asm volatile("s_waitcnt vmcnt(0)" ::: "memory");
    __syncthreads();

    // per-block-uniform output mapping (QKV tiles never straddle segments)
    const float* bp; u16* ob; int c0; bool elu;
    if (MODE == 4) {
        int seg = n0 >> 10;
        bp  = (seg == 0) ? bias : (seg == 1) ? biasK : biasV;
        ob  = (seg == 0) ? out  : (seg == 1) ? outK  : outV;
        c0  = n0 & 1023;
        elu = (seg < 2);
    } else { bp = bias; ob = out; c0 = n0; elu = false; }

    u16* Ct = shm;   // [256][264] bf16, 16B-aligned rows (528B stride)
#pragma unroll
    for (int j = 0; j < 4; j++) {
        int cl   = wn * 64 + j * 16 + lm;
        float bvl = bp[c0 + cl];
#pragma unroll
        for (int i = 0; i < 8; i++) {
            int rl = wm * 128 + i * 16 + quad * 4;
#pragma unroll
            for (int r = 0; r < 4; r++) {
                float z = acc[i][j][r] + bvl;
                float o;
                if (MODE == 2)      o = gelu_f(gelu_f(z));
                else if (MODE == 3) o = gelu_f(z);
                else if (MODE == 4) o = elu ? ((z > 0.f) ? z + 1.f : __expf(z)) : z;
                else                o = z;
                Ct[(rl + r) * 264 + cl] = f2bf(o);
            }
        }
    }
    __syncthreads();

    // coalesced stores: thread t -> row t>>1, col-half (t&1)*128; 16x dwordx4
    {
        int row = t >> 1;
        int ch  = (t & 1) * 128;
        const u16* src = Ct + row * 264 + ch;
        u16* dst = ob + (size_t)(m0 + row) * ldo + c0 + ch;
#pragma unroll
        for (int cc = 0; cc < 128; cc += 8)
            *(uint4*)(dst + cc) = *(const uint4*)(src + cc);
    }
}

// ---------------- KV / Ksum reduction over S (4 h per thread, ushort4) -------
__global__ __launch_bounds__(256) void kv_reduce(const u16* __restrict__ Kb,
                                                 const u16* __restrict__ vb,
                                                 float* __restrict__ KV,
                                                 float* __restrict__ Ks) {
    int n  = blockIdx.z;
    int h  = threadIdx.x * 4;          // A_ = 1024 = 256 threads * 4
    int s0 = blockIdx.y * 128;
    const u16* kp = Kb + (size_t)n * S_ * A_ + (size_t)s0 * A_ + h;
    const u16* vp = vb + (size_t)n * S_ * A_ + (size_t)s0 * A_ + h;
    float kv0 = 0.f, kv1 = 0.f, kv2 = 0.f, kv3 = 0.f;
    float ks0 = 0.f, ks1 = 0.f, ks2 = 0.f, ks3 = 0.f;
#pragma unroll 4
    for (int s = 0; s < 128; s++) {
        ushort4 k4 = *(const ushort4*)(kp + (size_t)s * A_);
        ushort4 v4 = *(const ushort4*)(vp + (size_t)s * A_);
        float k0 = bf2f(k4.x), k1 = bf2f(k4.y), k2 = bf2f(k4.z), k3 = bf2f(k4.w);
        kv0 += k0 * bf2f(v4.x); kv1 += k1 * bf2f(v4.y);
        kv2 += k2 * bf2f(v4.z); kv3 += k3 * bf2f(v4.w);
        ks0 += k0; ks1 += k1; ks2 += k2; ks3 += k3;
    }
    int base = n * A_ + h;
    atomicAdd(&KV[base + 0], kv0); atomicAdd(&KV[base + 1], kv1);
    atomicAdd(&KV[base + 2], kv2); atomicAdd(&KV[base + 3], kv3);
    atomicAdd(&Ks[base + 0], ks0); atomicAdd(&Ks[base + 1], ks1);
    atomicAdd(&Ks[base + 2], ks2); atomicAdd(&Ks[base + 3], ks3);
}

// ---------------- elementwise linear-attention output ------------------------
__global__ __launch_bounds__(256) void linattn_ew(const u16* __restrict__ Qb,
                                                  const float* __restrict__ KV,
                                                  const float* __restrict__ Ks,
                                                  u16* __restrict__ vout) {
    size_t idx = ((size_t)blockIdx.x * 256 + threadIdx.x) * 4;
    int n = (int)(idx >> 22);          // S_*A_ = 2^22
    int h = (int)(idx & (A_ - 1));
    ushort4 q4 = *(const ushort4*)(Qb + idx);
    int base = n * A_ + h;
    float4 kv4 = *(const float4*)(KV + base);
    float4 ks4 = *(const float4*)(Ks + base);
    float q0 = bf2f(q4.x), q1 = bf2f(q4.y), q2 = bf2f(q4.z), q3 = bf2f(q4.w);
    float o0 = q0 * kv4.x / (q0 * ks4.x + 1e-6f);
    float o1 = q1 * kv4.y / (q1 * ks4.y + 1e-6f);
    float o2 = q2 * kv4.z / (q2 * ks4.z + 1e-6f);
    float o3 = q3 * kv4.w / (q3 * ks4.w + 1e-6f);
    ushort4 o;
    o.x = f2bf(o0); o.y = f2bf(o1); o.z = f2bf(o2); o.w = f2bf(o3);
    *(ushort4*)(vout + idx) = o;
}

// ---------------- x init: f32 copy (residual) + bf16 cast --------------------
__global__ __launch_bounds__(256) void convert_x(const float* __restrict__ x,
                                                 float* __restrict__ xf,
                                                 u16* __restrict__ xb) {
    size_t idx = ((size_t)blockIdx.x * 256 + threadIdx.x) * 4;
    float4 v = *(const float4*)(x + idx);
    *(float4*)(xf + idx) = v;
    ushort4 o;
    o.x = f2bf(v.x); o.y = f2bf(v.y); o.z = f2bf(v.z); o.w = f2bf(v.w);
    *(ushort4*)(xb + idx) = o;
}

// ---------------- fused residual + LayerNorm (vectorized, shuffle reduce) ----
// NOTE: y/xb and res/xf may alias (in-place); each thread reads its elements
// before the first barrier and writes them only after the second -> safe.
__global__ __launch_bounds__(256) void ln_fused(const u16* y,
                                                const float* res,
                                                const float* sc,
                                                const float* bs,
                                                float* xf,
                                                u16* xb) {
    __shared__ float wred[8];
    int row = blockIdx.x;
    int t   = threadIdx.x;
    int lane = t & 63, wid = t >> 6;
    const u16*   yp = y   + (size_t)row * D_;
    const float* rp = res + (size_t)row * D_;
    ushort4 y4 = *(const ushort4*)(yp + t * 4);
    float4  r4 = *(const float4*)(rp + t * 4);
    float v0 = bf2f(y4.x) + r4.x;
    float v1 = bf2f(y4.y) + r4.y;
    float v2 = bf2f(y4.z) + r4.z;
    float v3 = bf2f(y4.w) + r4.w;
    float s = v0 + v1 + v2 + v3;
#pragma unroll
    for (int o = 32; o; o >>= 1) s += __shfl_down(s, o, 64);
    if (lane == 0) wred[wid] = s;
    __syncthreads();
    float mean = (wred[0] + wred[1] + wred[2] + wred[3]) * (1.0f / D_);
    float d0 = v0 - mean, d1 = v1 - mean, d2 = v2 - mean, d3 = v3 - mean;
    float q = d0 * d0 + d1 * d1 + d2 * d2 + d3 * d3;
#pragma unroll
    for (int o = 32; o; o >>= 1) q += __shfl_down(q, o, 64);
    if (lane == 0) wred[wid + 4] = q;
    __syncthreads();
    float rstd = rsqrtf((wred[4] + wred[5] + wred[6] + wred[7]) * (1.0f / D_) + LN_EPS);
    float4 s4 = *(const float4*)(sc + t * 4);
    float4 b4 = *(const float4*)(bs + t * 4);
    float o0 = d0 * rstd * s4.x + b4.x;
    float o1 = d1 * rstd * s4.y + b4.y;
    float o2 = d2 * rstd * s4.z + b4.z;
    float o3 = d3 * rstd * s4.w + b4.w;
    *(float4*)(xf + (size_t)row * D_ + t * 4) = (float4){o0, o1, o2, o3};
    ushort4 ob;
    ob.x = f2bf(o0); ob.y = f2bf(o1); ob.z = f2bf(o2); ob.w = f2bf(o3);
    *(ushort4*)(xb + (size_t)row * D_ + t * 4) = ob;
}

extern "C" void kernel_launch(void* const* d_in, const int* in_sizes, int n_in,
                              void* d_out, int out_size, void* d_ws, size_t ws_size,
                              hipStream_t stream) {
    const float* x_in = (const float*)d_in[0];
    const float* Wq   = (const float*)d_in[1];
    const float* bq   = (const float*)d_in[2];
    const float* Wk   = (const float*)d_in[3];
    const float* bk   = (const float*)d_in[4];
    const float* Wv   = (const float*)d_in[5];
    const float* bv   = (const float*)d_in[6];
    const float* Wo   = (const float*)d_in[7];
    const float* bo   = (const float*)d_in[8];
    const float* ln1s = (const float*)d_in[9];
    const float* ln1b = (const float*)d_in[10];
    const float* W1   = (const float*)d_in[11];
    const float* b1   = (const float*)d_in[12];
    const float* W2   = (const float*)d_in[13];
    const float* b2   = (const float*)d_in[14];
    const float* ln2s = (const float*)d_in[15];
    const float* ln2b = (const float*)d_in[16];

    const size_t MB = 1024 * 1024;
    char* ws = (char*)d_ws;
    // Workspace layout: 176 MB total.
    //   0- 32 : xb   bf16 x (GEMM A); FF2 writes f here in-place
    //  32- 64 : Qb   bf16 Q                      } dead by FF time ->
    //  64- 96 : Kb   bf16 K, then Vattn          }  overlaid by
    //  96-128 : vb   bf16 v, then a (Wo output)  }  hidden [16384][4096]
    // 128-134 : WtQKV bf16 [3072][1024]          }  (128 MB @ 32..160)
    // 134-136 : Wot  bf16 [1024][1024]           }
    // 136-...: kvb  KV+Ksum 32 KB                }
    // 160-168 : W1t  bf16 [4096][1024]   (live through FF)
    // 168-176 : W2t  bf16 [1024][4096]   (live through FF)
    float* xf    = (float*)d_out;            // 64 MB fp32 residual / final out
    u16*   xb    = (u16*)(ws);
    u16*   Qb    = (u16*)(ws + 32 * MB);
    u16*   Kb    = (u16*)(ws + 64 * MB);
    u16*   vb    = (u16*)(ws + 96 * MB);
    u16*   hid   = (u16*)(ws + 32 * MB);     // [16384][4096] bf16, 128 MB
    u16*   WtQKV = (u16*)(ws + 128 * MB);
    u16*   Wot   = (u16*)(ws + 134 * MB);
    float* kvb   = (float*)(ws + 136 * MB);
    u16*   W1t   = (u16*)(ws + 160 * MB);
    u16*   W2t   = (u16*)(ws + 168 * MB);
    float* KV    = kvb;
    float* Ks    = kvb + B_ * A_;

    const int M = B_ * S_;   // 16384

    convert_x<<<dim3(M * D_ / 1024), 256, 0, stream>>>(x_in, xf, xb);

    for (int i = 0; i < NB; i++) {
        const float* Wq_i = Wq + (size_t)i * D_ * A_;
        const float* Wk_i = Wk + (size_t)i * D_ * A_;
        const float* Wv_i = Wv + (size_t)i * D_ * A_;
        const float* Wo_i = Wo + (size_t)i * A_ * D_;
        const float* W1_i = W1 + (size_t)i * D_ * FF_;
        const float* W2_i = W2 + (size_t)i * FF_ * D_;

        // weight transposes (bf16 downcast) for this block
        transpose_w<<<dim3(A_ / 32, D_ / 32), dim3(32, 8), 0, stream>>>(Wq_i, WtQKV, D_, A_);
        transpose_w<<<dim3(A_ / 32, D_ / 32), dim3(32, 8), 0, stream>>>(Wk_i, WtQKV + (size_t)A_ * D_, D_, A_);
        transpose_w<<<dim3(A_ / 32, D_ / 32), dim3(32, 8), 0, stream>>>(Wv_i, WtQKV + (size_t)2 * A_ * D_, D_, A_);
        transpose_w<<<dim3(D_ / 32, A_ / 32), dim3(32, 8), 0, stream>>>(Wo_i, Wot, A_, D_);
        transpose_w<<<dim3(FF_ / 32, D_ / 32), dim3(32, 8), 0, stream>>>(W1_i, W1t, D_, FF_);
        transpose_w<<<dim3(D_ / 32, FF_ / 32), dim3(32, 8), 0, stream>>>(W2_i, W2t, FF_, D_);

        // fused QKV: [16384,1024] @ [1024,3072] -> Q(elu+1), K(elu+1), v(id)
        gemm256<4><<<dim3(12 * 64), 512, 0, stream>>>(
            xb, WtQKV, bq + i * A_, Qb, M, 3072, D_, 12, 1024,
            Kb, vb, bk + i * A_, bv + i * A_);

        // KV[n,h] = sum_s K*v ; Ksum[n,h] = sum_s K
        zero_kv<<<dim3(8), 256, 0, stream>>>(kvb);
        kv_reduce<<<dim3(1, S_ / 128, B_), 256, 0, stream>>>(Kb, vb, KV, Ks);

        // Vattn = Q*KV / (Q*Ksum + 1e-6)  (overwrites Kb)
        linattn_ew<<<dim3(M * A_ / 1024), 256, 0, stream>>>(Qb, KV, Ks, Kb);

        // a = gelu(gelu(Vattn@Wo + bo)) -> vb
        gemm256<2><<<dim3(4 * 64), 512, 0, stream>>>(
            Kb, Wot, bo + i * D_, vb, M, D_, A_, 4, 1024,
            nullptr, nullptr, nullptr, nullptr);

        // x = LN(a + residual)
        ln_fused<<<dim3(M), 256, 0, stream>>>(vb, xf, ln1s + i * D_, ln1b + i * D_, xf, xb);

        // FF: h = gelu(x@W1+b1) full [16384][4096]; f = gelu(h@W2+b2) -> xb
        gemm256<3><<<dim3(16 * 64), 512, 0, stream>>>(
            xb, W1t, b1 + (size_t)i * FF_, hid, M, FF_, D_, 16, 4096,
            nullptr, nullptr, nullptr, nullptr);
        gemm256<3><<<dim3(4 * 64), 512, 0, stream>>>(
            hid, W2t, b2 + i * D_, xb, M, D_, FF_, 4, 1024,
            nullptr, nullptr, nullptr, nullptr);

        // x = LN(f + residual)  (xb in-place; final block writes d_out via xf)
        ln_fused<<<dim3(M), 256, 0, stream>>>(xb, xf, ln2s + i * D_, ln2b + i * D_, xf, xb);
    }
}